// Round 18
// baseline (352.100 us; speedup 1.0000x reference)
//
#include <hip/hip_runtime.h>
#include <hip/hip_bf16.h>

typedef __hip_bfloat16 bf16;
typedef __attribute__((ext_vector_type(8))) short short8;
typedef __attribute__((ext_vector_type(8))) __bf16 bf16x8;
typedef __attribute__((ext_vector_type(4))) float f32x4;

#define RT_ROWS 17408
#define SH0_ROW 17408
#define SH1_ROW 25600
#define ROWCAP  33792
#define NTILES  264
#define NCHUNK  288     // flash chunks per bh (Q-blocks of 32 rows, bands 8x{1..8})
#define NPART   280     // chunks that write partials (bands 1-7)

static __device__ __forceinline__ f32x4 mfma16(short8 a, short8 b, f32x4 c) {
  return __builtin_amdgcn_mfma_f32_16x16x32_bf16(
      __builtin_bit_cast(bf16x8, a), __builtin_bit_cast(bf16x8, b), c, 0, 0, 0);
}

static __device__ __forceinline__ void gload16(const bf16* g, void* l) {
  __builtin_amdgcn_global_load_lds(
      (const __attribute__((address_space(1))) void*)g,
      (__attribute__((address_space(3))) void*)l, 16, 0, 0);
}

static __device__ __forceinline__ float b2f(short s) {
  unsigned u = ((unsigned)(unsigned short)s) << 16;
  return __builtin_bit_cast(float, u);
}

// ---------------- elementwise f32 -> bf16 ----------------
__global__ __launch_bounds__(256) void k_f32_to_bf16(const float* __restrict__ in,
                                                     bf16* __restrict__ out, int n) {
  int i = blockIdx.x * 256 + threadIdx.x;
  if (i < n) out[i] = __float2bfloat16(in[i]);
}

// ---------------- ALL weight transposes in one kernel ----------------
struct TD { const float* src; bf16* dst; int K, N, ldo, bx, bxy, start; long inZ, outZ; };
struct Tall { TD d[9]; };

__global__ __launch_bounds__(256) void k_transpose_all(Tall T) {
  int gid = blockIdx.x;
  int si = 0;
  #pragma unroll
  for (int i = 1; i < 9; ++i)
    if (gid >= T.d[i].start) si = i;
  TD dd = T.d[si];
  int local = gid - dd.start;
  int z = local / dd.bxy, rem = local - z * dd.bxy;
  int k0 = (rem % dd.bx) * 64, n0 = (rem / dd.bx) * 64;
  const float* in = dd.src + (size_t)z * dd.inZ;
  bf16* out = dd.dst + (size_t)z * dd.outZ;
  __shared__ bf16 t[64][65];
  for (int rep = 0; rep < 16; ++rep) {
    int lin = rep * 256 + threadIdx.x;
    int i = lin >> 6, j = lin & 63;
    if (k0 + i < dd.K && n0 + j < dd.N)
      t[i][j] = __float2bfloat16(in[(size_t)(k0 + i) * dd.N + n0 + j]);
  }
  __syncthreads();
  for (int rep = 0; rep < 16; ++rep) {
    int lin = rep * 256 + threadIdx.x;
    int jj = lin >> 6, ii = lin & 63;
    if (n0 + jj < dd.N && k0 + ii < dd.K)
      out[(size_t)(n0 + jj) * dd.ldo + k0 + ii] = t[ii][jj];
  }
}

// ---------------- shared dense NT GEMM core ----------------
static __device__ __forceinline__ void gemm_core(
    const bf16* __restrict__ A, const bf16* __restrict__ BT,
    int N, int K, int lda, int ldb, int ldc,
    float* __restrict__ Cf, bf16* __restrict__ Cb) {
  __shared__ __align__(16) bf16 As[128 * 32];
  __shared__ __align__(16) bf16 Bs[128 * 32];
  const int m0 = blockIdx.x * 128, n0 = blockIdx.y * 128;
  const int tid = threadIdx.x, lane = tid & 63, wave = tid >> 6;
  const int wr = (wave >> 1) * 64, wc = (wave & 1) * 64;
  const int lr = lane & 15;
  const int kgs = (((lane >> 4) ^ ((lane >> 1) & 3)) << 3);
  const int srow = wave * 16 + (lane >> 2);
  const int scol = (((lane & 3) ^ ((lane >> 3) & 3)) << 3);
  const bf16* Ab = A + (size_t)(m0 + srow) * lda + scol;
  const bf16* Bb = BT + (size_t)(n0 + srow) * ldb + scol;
  char* AsL = (char*)As + wave * 1024;
  char* BsL = (char*)Bs + wave * 1024;

  f32x4 acc[4][4];
  for (int i = 0; i < 4; ++i)
    for (int j = 0; j < 4; ++j) acc[i][j] = f32x4{0.f, 0.f, 0.f, 0.f};

  for (int k0 = 0; k0 < K; k0 += 32) {
    __syncthreads();
    gload16(Ab + k0, AsL);
    gload16(Ab + (size_t)64 * lda + k0, AsL + 4096);
    gload16(Bb + k0, BsL);
    gload16(Bb + (size_t)64 * ldb + k0, BsL + 4096);
    __syncthreads();
    short8 af[4], bfr[4];
    for (int i = 0; i < 4; ++i) af[i] = *(const short8*)&As[(wr + i * 16 + lr) * 32 + kgs];
    for (int j = 0; j < 4; ++j) bfr[j] = *(const short8*)&Bs[(wc + j * 16 + lr) * 32 + kgs];
    for (int i = 0; i < 4; ++i)
      for (int j = 0; j < 4; ++j)
        acc[i][j] = mfma16(af[i], bfr[j], acc[i][j]);
  }

  for (int i = 0; i < 4; ++i) {
    int mb = m0 + wr + i * 16 + (lane >> 4) * 4;
    for (int j = 0; j < 4; ++j) {
      int n = n0 + wc + j * 16 + lr;
      if (n >= N) continue;
      for (int r = 0; r < 4; ++r) {
        size_t idx = (size_t)(mb + r) * ldc + n;
        float v = acc[i][j][r];
        if (Cf) Cf[idx] = v;
        else Cb[idx] = __float2bfloat16(v);
      }
    }
  }
}

__global__ __launch_bounds__(256) void k_gemm_dq(
    const bf16* A, const bf16* BT, int N, int K, int lda, int ldb, int ldc, float* Cf) {
  gemm_core(A, BT, N, K, lda, ldb, ldc, Cf, nullptr);
}
__global__ __launch_bounds__(256) void k_gemm_kv(
    const bf16* A, const bf16* BT, int N, int K, int lda, int ldb, int ldc, bf16* Cb) {
  gemm_core(A, BT, N, K, lda, ldb, ldc, nullptr, Cb);
}
__global__ __launch_bounds__(256) void k_gemm_wo(
    const bf16* A, const bf16* BT, int N, int K, int lda, int ldb, int ldc, bf16* Cb) {
  gemm_core(A, BT, N, K, lda, ldb, ldc, nullptr, Cb);
}

// ---------------- q-projection GEMM with FUSED rope epilogue -> qf ---------------
__global__ __launch_bounds__(256) void k_gemm_q(
    const bf16* __restrict__ A, const bf16* __restrict__ BT,
    const float* __restrict__ tab, bf16* __restrict__ qf) {
  const int K = 192, lda = 192, ldb = 192;
  __shared__ __align__(16) bf16 As[128 * 32];
  __shared__ __align__(16) bf16 Bs[128 * 32];
  const int m0 = blockIdx.x * 128, n0 = blockIdx.y * 128;
  const int tid = threadIdx.x, lane = tid & 63, wave = tid >> 6;
  const int wr = (wave >> 1) * 64, wc = (wave & 1) * 64;
  const int lr = lane & 15;
  const int kgs = (((lane >> 4) ^ ((lane >> 1) & 3)) << 3);
  const int srow = wave * 16 + (lane >> 2);
  const int scol = (((lane & 3) ^ ((lane >> 3) & 3)) << 3);
  const bf16* Ab = A + (size_t)(m0 + srow) * lda + scol;
  const bf16* Bb = BT + (size_t)(n0 + srow) * ldb + scol;
  char* AsL = (char*)As + wave * 1024;
  char* BsL = (char*)Bs + wave * 1024;

  f32x4 acc[4][4];
  for (int i = 0; i < 4; ++i)
    for (int j = 0; j < 4; ++j) acc[i][j] = f32x4{0.f, 0.f, 0.f, 0.f};

  for (int k0 = 0; k0 < K; k0 += 32) {
    __syncthreads();
    gload16(Ab + k0, AsL);
    gload16(Ab + (size_t)64 * lda + k0, AsL + 4096);
    gload16(Bb + k0, BsL);
    gload16(Bb + (size_t)64 * ldb + k0, BsL + 4096);
    __syncthreads();
    short8 af[4], bfr[4];
    for (int i = 0; i < 4; ++i) af[i] = *(const short8*)&As[(wr + i * 16 + lr) * 32 + kgs];
    for (int j = 0; j < 4; ++j) bfr[j] = *(const short8*)&Bs[(wc + j * 16 + lr) * 32 + kgs];
    for (int i = 0; i < 4; ++i)
      for (int j = 0; j < 4; ++j)
        acc[i][j] = mfma16(af[i], bfr[j], acc[i][j]);
  }

  #pragma unroll
  for (int i = 0; i < 4; ++i) {
    int mb = m0 + wr + i * 16 + (lane >> 4) * 4;
    #pragma unroll
    for (int j = 0; j < 4; ++j) {
      int n = n0 + wc + j * 16 + lr;
      int h = (n >= 288) ? 3 : ((n >= 192) ? 2 : ((n >= 96) ? 1 : 0));
      int d = n - h * 96;
      #pragma unroll
      for (int r = 0; r < 4; ++r) {
        int t = mb + r;
        int s = t & 2047;
        float v;
        if (d < 64) {
          v = acc[i][j][r];
        } else {
          float c = tab[s * 32 + lr], sn = tab[s * 32 + 16 + lr];
          if (d < 80) {
            float x1 = acc[i][j][r];
            float x2 = (j < 3) ? acc[i][j + 1][r] : 0.f;
            v = x1 * c - x2 * sn;
          } else {
            float x1 = (j > 0) ? acc[i][j - 1][r] : 0.f;
            float x2 = acc[i][j][r];
            v = x2 * c + x1 * sn;
          }
        }
        size_t bh = (size_t)(t >> 11) * 4 + h;
        qf[bh * (2048 * 96) + (size_t)s * 96 + d] = __float2bfloat16(v);
      }
    }
  }
}

// ---------------- grouped expert GEMM: 2-phase double-buffered pipeline ----------
// T3 minimum-2-phase recipe: STAGE(next) issued BEFORE compute(cur); single
// vmcnt(0)+s_barrier per tile at iteration end -> loads fly under MFMA phase.
template <int ACT>
__global__ __launch_bounds__(256) void k_gemm_grouped(
    const bf16* __restrict__ A, const int* __restrict__ rowtok,
    const int* __restrict__ tileexp, const bf16* __restrict__ W, size_t wstride,
    int N, int K, int lda, bf16* __restrict__ out, int ldo) {
  int bx = (int)blockIdx.x;
  const int tl = (bx & 7) * 33 + (bx >> 3);   // XCD x owns tiles [33x, 33x+33)
  const int ex = tileexp[tl];
  if (ex < 0) return;
  __shared__ __align__(16) bf16 As[2][128 * 32];
  __shared__ __align__(16) bf16 Bs[2][128 * 32];
  const int m0 = tl * 128, n0 = blockIdx.y * 128;
  const int tid = threadIdx.x, lane = tid & 63, wave = tid >> 6;
  const int wr = (wave >> 1) * 64, wc = (wave & 1) * 64;
  const int lr = lane & 15;
  const int kgs = (((lane >> 4) ^ ((lane >> 1) & 3)) << 3);
  const int srow = wave * 16 + (lane >> 2);
  const int scol = (((lane & 3) ^ ((lane >> 3) & 3)) << 3);

  int ar0 = m0 + srow, ar1 = ar0 + 64;
  if (rowtok) {
    int t0 = rowtok[ar0]; ar0 = (t0 < 0) ? 0 : t0;
    int t1 = rowtok[ar1]; ar1 = (t1 < 0) ? 0 : t1;
  }
  const bf16* A0 = A + (size_t)ar0 * lda + scol;
  const bf16* A1 = A + (size_t)ar1 * lda + scol;
  const bf16* BT = W + (size_t)ex * wstride;
  const bf16* B0 = BT + (size_t)(n0 + srow) * K + scol;
  const bf16* B1 = B0 + (size_t)64 * K;

  auto stage = [&](int buf, int k0) {
    char* AsL = (char*)As[buf] + wave * 1024;
    char* BsL = (char*)Bs[buf] + wave * 1024;
    gload16(A0 + k0, AsL);
    gload16(A1 + k0, AsL + 4096);
    gload16(B0 + k0, BsL);
    gload16(B1 + k0, BsL + 4096);
  };

  f32x4 acc[4][4];
  for (int i = 0; i < 4; ++i)
    for (int j = 0; j < 4; ++j) acc[i][j] = f32x4{0.f, 0.f, 0.f, 0.f};

  // prologue: tile 0
  stage(0, 0);
  asm volatile("s_waitcnt vmcnt(0)" ::: "memory");
  __builtin_amdgcn_s_barrier();

  int cur = 0;
  for (int k0 = 32; k0 < K; k0 += 32) {
    stage(cur ^ 1, k0);                         // prefetch next tile (in flight below)
    short8 af[4], bfr[4];
    #pragma unroll
    for (int i = 0; i < 4; ++i) af[i] = *(const short8*)&As[cur][(wr + i * 16 + lr) * 32 + kgs];
    #pragma unroll
    for (int j = 0; j < 4; ++j) bfr[j] = *(const short8*)&Bs[cur][(wc + j * 16 + lr) * 32 + kgs];
    #pragma unroll
    for (int i = 0; i < 4; ++i)
      #pragma unroll
      for (int j = 0; j < 4; ++j)
        acc[i][j] = mfma16(af[i], bfr[j], acc[i][j]);
    asm volatile("s_waitcnt vmcnt(0)" ::: "memory");  // prefetched tile landed
    __builtin_amdgcn_s_barrier();                     // visible to all waves
    cur ^= 1;
  }
  // tail tile (no prefetch)
  {
    short8 af[4], bfr[4];
    #pragma unroll
    for (int i = 0; i < 4; ++i) af[i] = *(const short8*)&As[cur][(wr + i * 16 + lr) * 32 + kgs];
    #pragma unroll
    for (int j = 0; j < 4; ++j) bfr[j] = *(const short8*)&Bs[cur][(wc + j * 16 + lr) * 32 + kgs];
    #pragma unroll
    for (int i = 0; i < 4; ++i)
      #pragma unroll
      for (int j = 0; j < 4; ++j)
        acc[i][j] = mfma16(af[i], bfr[j], acc[i][j]);
  }

  for (int i = 0; i < 4; ++i) {
    int mb = m0 + wr + i * 16 + (lane >> 4) * 4;
    for (int j = 0; j < 4; ++j) {
      int n = n0 + wc + j * 16 + lr;
      for (int r = 0; r < 4; ++r) {
        float v = acc[i][j][r];
        if (ACT) v = v / (1.f + __expf(-v));
        out[(size_t)(mb + r) * ldo + n] = __float2bfloat16(v);
      }
    }
  }
}

// ---------------- post GEMM0: rmsnorms + split, write kv output (f32) ----------------
__global__ __launch_bounds__(256) void k_postproj1(
    const float* __restrict__ tmp, const float* __restrict__ qnw,
    const float* __restrict__ kvnw, bf16* __restrict__ cq,
    bf16* __restrict__ kvn, float* __restrict__ krope, float* __restrict__ kvout) {
  int t = blockIdx.x * 4 + (threadIdx.x >> 6);
  int lane = threadIdx.x & 63;
  const float* row = tmp + (size_t)t * 352;
  float s1 = 0.f, s2 = 0.f;
  for (int d = lane; d < 192; d += 64) { float v = row[d]; s1 += v * v; }
  for (int d = lane; d < 128; d += 64) { float v = row[192 + d]; s2 += v * v; }
  for (int o = 32; o > 0; o >>= 1) { s1 += __shfl_xor(s1, o); s2 += __shfl_xor(s2, o); }
  float r1 = rsqrtf(s1 / 192.f + 1e-6f);
  float r2 = rsqrtf(s2 / 128.f + 1e-6f);
  for (int d = lane; d < 192; d += 64)
    cq[(size_t)t * 192 + d] = __float2bfloat16(row[d] * r1 * qnw[d]);
  for (int d = lane; d < 128; d += 64)
    kvn[(size_t)t * 128 + d] = __float2bfloat16(row[192 + d] * r2 * kvnw[d]);
  for (int d = lane; d < 160; d += 64)
    kvout[(size_t)t * 160 + d] = row[192 + d];
  if (lane < 32) krope[(size_t)t * 32 + lane] = row[320 + lane];
}

// ---------------- rope cos/sin table ----------------
__global__ __launch_bounds__(256) void k_rope_table(float* __restrict__ tab) {
  int idx = blockIdx.x * 256 + threadIdx.x;  // 2048*16
  int s = idx >> 4, jm = idx & 15;
  float invf = expf(-(float)jm * 0.575646273f);
  float ang = (float)s * invf;
  tab[s * 32 + jm] = cosf(ang);
  tab[s * 32 + 16 + jm] = sinf(ang);
}

// ---------------- k: nope copy + shared roped k_rope ----------------
__global__ __launch_bounds__(256) void k_make_kf(const bf16* __restrict__ kvbig,
                                                 const float* __restrict__ krope,
                                                 const float* __restrict__ tab,
                                                 bf16* __restrict__ kf) {
  int idx = blockIdx.x * 256 + threadIdx.x;
  int t = idx / 384, hd = idx - t * 384;
  int h = hd / 96, d = hd - h * 96;
  int s = t & 2047;
  bf16 outv;
  if (d < 64) outv = kvbig[(size_t)t * 768 + h * 192 + d];
  else {
    int j = d - 64, jm = j & 15;
    float c = tab[s * 32 + jm], sn = tab[s * 32 + 16 + jm];
    float x1 = krope[(size_t)t * 32 + jm], x2 = krope[(size_t)t * 32 + 16 + jm];
    float v = (j < 16) ? (x1 * c - x2 * sn) : (x2 * c + x1 * sn);
    outv = __float2bfloat16(v);
  }
  size_t bh = (size_t)(t >> 11) * 4 + h;
  kf[bh * (2048 * 96) + (size_t)s * 96 + d] = outv;
}

// ---------------- v: extract + transpose to [bh][d=128][s=2048] ----------------
__global__ __launch_bounds__(256) void k_make_vT(const bf16* __restrict__ kvbig,
                                                 bf16* __restrict__ vT) {
  __shared__ bf16 t[64][136];
  int bh = blockIdx.y;
  int b = bh >> 2, h = bh & 3;
  int s0 = blockIdx.x * 64;
  for (int rep = 0; rep < 4; ++rep) {
    int lin = rep * 256 + threadIdx.x;
    int i = lin >> 4, jc = (lin & 15) * 8;
    short8 v = *(const short8*)(kvbig + (size_t)(b * 2048 + s0 + i) * 768 + h * 192 + 64 + jc);
    *(short8*)&t[i][jc] = v;
  }
  __syncthreads();
  for (int rep = 0; rep < 32; ++rep) {
    int lin = rep * 256 + threadIdx.x;
    int d = lin >> 6, i = lin & 63;
    vT[((size_t)bh * 128 + d) * 2048 + s0 + i] = t[i][d];
  }
}

// ---------------- flash attention: 1D grid 4608, bh-per-XCD locality -------------
__global__ __launch_bounds__(64, 2) void k_flash(const bf16* __restrict__ qf,
                                                 const bf16* __restrict__ kf,
                                                 const bf16* __restrict__ vT,
                                                 bf16* __restrict__ attn,
                                                 bf16* __restrict__ pO,
                                                 float* __restrict__ pML) {
  const int lin = (int)blockIdx.x;
  const int r16 = lin & 15;
  const int bh = ((r16 & 7) << 1) | (r16 >> 3);
  const int e = (NCHUNK - 1) - (lin >> 4);   // big-band chunks dispatch first
  int k = 0;
  #pragma unroll
  for (int kk = 1; kk < 8; ++kk)
    if (e >= 4 * kk * (kk + 1)) k = kk;
  const int rel = e - 4 * k * (k + 1);
  const int Q = 8 * k + rel / (k + 1);
  const int c = rel - (rel / (k + 1)) * (k + 1);
  const int nt = (Q >> 1) + 1;
  const int kt0 = 4 * c;
  const int kt1 = (kt0 + 4 < nt) ? kt0 + 4 : nt;
  const int q0 = Q * 32;
  const int lane = threadIdx.x;
  const int lr = lane & 15, hi = lane >> 4, kg = hi * 8;
  const bf16* Qp = qf + (size_t)bh * (2048 * 96);
  const bf16* Kp = kf + (size_t)bh * (2048 * 96);
  const bf16* Vt = vT + (size_t)bh * (128 * 2048);

  short8 qfr[2][3];
  for (int i = 0; i < 2; ++i)
    for (int ks = 0; ks < 3; ++ks)
      qfr[i][ks] = *(const short8*)(Qp + (size_t)(q0 + i * 16 + lr) * 96 + ks * 32 + kg);

  f32x4 o[2][8];
  for (int i = 0; i < 2; ++i)
    for (int j = 0; j < 8; ++j) o[i][j] = f32x4{0.f, 0.f, 0.f, 0.f};
  float mrow[2][4], lsum[2][4];
  for (int i = 0; i < 2; ++i)
    for (int r = 0; r < 4; ++r) { mrow[i][r] = -1e30f; lsum[i][r] = 0.f; }

  __shared__ bf16 plds[32][72];
  const float scale = 0.1020620726f;  // 1/sqrt(96)

  for (int kt = kt0; kt < kt1; ++kt) {
    int kv0 = kt * 64;
    f32x4 s[2][4];
    for (int i = 0; i < 2; ++i)
      for (int j = 0; j < 4; ++j) s[i][j] = f32x4{0.f, 0.f, 0.f, 0.f};
    for (int jh = 0; jh < 2; ++jh) {
      short8 kc[2][3];
      for (int jj = 0; jj < 2; ++jj)
        for (int ks = 0; ks < 3; ++ks)
          kc[jj][ks] = *(const short8*)(Kp + (size_t)(kv0 + (jh * 2 + jj) * 16 + lr) * 96 + ks * 32 + kg);
      for (int jj = 0; jj < 2; ++jj)
        for (int ks = 0; ks < 3; ++ks) {
          s[0][jh * 2 + jj] = mfma16(qfr[0][ks], kc[jj][ks], s[0][jh * 2 + jj]);
          s[1][jh * 2 + jj] = mfma16(qfr[1][ks], kc[jj][ks], s[1][jh * 2 + jj]);
        }
    }

    bool diag = (kt == nt - 1);
    for (int i = 0; i < 2; ++i)
      for (int j = 0; j < 4; ++j)
        for (int r = 0; r < 4; ++r) {
          float v = s[i][j][r] * scale;
          if (diag) {
            int qq = q0 + i * 16 + hi * 4 + r;
            int kk = kv0 + j * 16 + lr;
            if (kk > qq) v = -1e30f;
          }
          s[i][j][r] = v;
        }
    float vmax4[2][4], grow = -1e30f;
    for (int i = 0; i < 2; ++i)
      for (int r = 0; r < 4; ++r) {
        float v = fmaxf(fmaxf(s[i][0][r], s[i][1][r]), fmaxf(s[i][2][r], s[i][3][r]));
        v = fmaxf(v, __shfl_xor(v, 1));
        v = fmaxf(v, __shfl_xor(v, 2));
        v = fmaxf(v, __shfl_xor(v, 4));
        v = fmaxf(v, __shfl_xor(v, 8));
        vmax4[i][r] = v;
        grow = fmaxf(grow, v - mrow[i][r]);
      }
    if (!__all(grow <= 8.f)) {
      for (int i = 0; i < 2; ++i)
        for (int r = 0; r < 4; ++r) {
          float mnew = fmaxf(mrow[i][r], vmax4[i][r]);
          float alpha = __expf(mrow[i][r] - mnew);
          mrow[i][r] = mnew;
          lsum[i][r] *= alpha;
          for (int j = 0; j < 8; ++j) o[i][j][r] *= alpha;
        }
    }
    for (int i = 0; i < 2; ++i)
      for (int r = 0; r < 4; ++r) {
        float rs = 0.f;
        for (int j = 0; j < 4; ++j) {
          float p = __expf(s[i][j][r] - mrow[i][r]);
          s[i][j][r] = p;
          rs += p;
        }
        rs += __shfl_xor(rs, 1); rs += __shfl_xor(rs, 2);
        rs += __shfl_xor(rs, 4); rs += __shfl_xor(rs, 8);
        lsum[i][r] += rs;
      }
    // P via wave-private LDS roundtrip (1 wave: in-order DS pipe, no barrier)
    for (int i = 0; i < 2; ++i)
      for (int j = 0; j < 4; ++j)
        for (int r = 0; r < 4; ++r)
          plds[i * 16 + hi * 4 + r][j * 16 + lr] = __float2bfloat16(s[i][j][r]);
    short8 pf[2][2];
    for (int i = 0; i < 2; ++i) {
      pf[i][0] = *(const short8*)&plds[i * 16 + lr][kg];
      pf[i][1] = *(const short8*)&plds[i * 16 + lr][32 + kg];
    }
    for (int j = 0; j < 8; ++j) {
      short8 v0 = *(const short8*)(Vt + (size_t)(j * 16 + lr) * 2048 + kv0 + kg);
      short8 v1 = *(const short8*)(Vt + (size_t)(j * 16 + lr) * 2048 + kv0 + 32 + kg);
      o[0][j] = mfma16(pf[0][0], v0, o[0][j]);
      o[0][j] = mfma16(pf[0][1], v1, o[0][j]);
      o[1][j] = mfma16(pf[1][0], v0, o[1][j]);
      o[1][j] = mfma16(pf[1][1], v1, o[1][j]);
    }
  }

  if (k == 0) {
    int bb = bh >> 2, h = bh & 3;
    for (int i = 0; i < 2; ++i)
      for (int r = 0; r < 4; ++r) {
        int qq = q0 + i * 16 + hi * 4 + r;
        float inv = 1.f / lsum[i][r];
        size_t baseo = ((size_t)(bb * 2048 + qq)) * 512 + h * 128;
        for (int j = 0; j < 8; ++j)
          attn[baseo + j * 16 + lr] = __float2bfloat16(o[i][j][r] * inv);
      }
  } else {
    const int p = bh * NPART + (e - 8);
    for (int i = 0; i < 2; ++i)
      for (int r = 0; r < 4; ++r) {
        int qrl = i * 16 + hi * 4 + r;
        size_t baseo = (size_t)p * 4096 + (size_t)qrl * 128;
        for (int j = 0; j < 8; ++j)
          pO[baseo + j * 16 + lr] = __float2bfloat16(o[i][j][r]);
        if (lr == 0) {
          pML[p * 64 + qrl] = mrow[i][r];
          pML[p * 64 + 32 + qrl] = lsum[i][r];
        }
      }
  }
}

// ---------------- merge 2..8 partials per Q-block (bands 1-7) ----------------
__global__ __launch_bounds__(512) void k_merge(const bf16* __restrict__ pO,
                                               const float* __restrict__ pML,
                                               bf16* __restrict__ attn) {
  const int Q = 8 + blockIdx.x;  // 8..63
  const int bh = blockIdx.y;
  const int k = Q >> 3, np = k + 1;
  const int eb = 4 * k * (k + 1) + (Q - 8 * k) * (k + 1);
  const int pbase = bh * NPART + (eb - 8);
  const int qrl = threadIdx.x >> 4, d0 = (threadIdx.x & 15) * 8;
  float m[8], l[8], w[8];
  float mm = -1e30f;
  for (int i = 0; i < 8; ++i)
    if (i < np) {
      m[i] = pML[(pbase + i) * 64 + qrl];
      l[i] = pML[(pbase + i) * 64 + 32 + qrl];
      mm = fmaxf(mm, m[i]);
    }
  float L = 0.f;
  for (int i = 0; i < 8; ++i)
    if (i < np) { w[i] = __expf(m[i] - mm); L += l[i] * w[i]; }
  float inv = 1.f / L;
  float acc[8];
  for (int u = 0; u < 8; ++u) acc[u] = 0.f;
  for (int i = 0; i < 8; ++i)
    if (i < np) {
      short8 v = *(const short8*)(pO + (size_t)(pbase + i) * 4096 + (size_t)qrl * 128 + d0);
      for (int u = 0; u < 8; ++u) acc[u] += b2f(v[u]) * w[i];
    }
  int bb = bh >> 2, h = bh & 3;
  int q = Q * 32 + qrl;
  size_t ob = ((size_t)(bb * 2048 + q)) * 512 + h * 128 + d0;
  for (int u = 0; u < 8; ++u)
    attn[ob + u] = __float2bfloat16(acc[u] * inv);
}

// ---------------- fused residual + rmsnorm#2 + gating ----------------
__global__ __launch_bounds__(256) void k_norm2g(const float* __restrict__ x,
                                                const bf16* __restrict__ wo,
                                                const float* __restrict__ w,
                                                const float* __restrict__ Wg,
                                                float* __restrict__ x2f,
                                                bf16* __restrict__ x2b,
                                                int* __restrict__ tokexp,
                                                float* __restrict__ tokgate) {
  int wv = threadIdx.x >> 6, lane = threadIdx.x & 63;
  int t = blockIdx.x * 4 + wv;
  const float* row = x + (size_t)t * 512;
  int d0 = lane * 8;
  float v[8];
  {
    float4 a = *(const float4*)(row + d0);
    float4 bb = *(const float4*)(row + d0 + 4);
    short8 wv8 = *(const short8*)(wo + (size_t)t * 512 + d0);
    v[0] = a.x + b2f(wv8[0]); v[1] = a.y + b2f(wv8[1]);
    v[2] = a.z + b2f(wv8[2]); v[3] = a.w + b2f(wv8[3]);
    v[4] = bb.x + b2f(wv8[4]); v[5] = bb.y + b2f(wv8[5]);
    v[6] = bb.z + b2f(wv8[6]); v[7] = bb.w + b2f(wv8[7]);
  }
  float ss = 0.f;
  for (int u = 0; u < 8; ++u) ss += v[u] * v[u];
  for (int o = 32; o > 0; o >>= 1) ss += __shfl_xor(ss, o);
  float rr = rsqrtf(ss / 512.f + 1e-6f);
  {
    float4 a = *(const float4*)(w + d0);
    float4 bb = *(const float4*)(w + d0 + 4);
    v[0] *= rr * a.x; v[1] *= rr * a.y; v[2] *= rr * a.z; v[3] *= rr * a.w;
    v[4] *= rr * bb.x; v[5] *= rr * bb.y; v[6] *= rr * bb.z; v[7] *= rr * bb.w;
  }
  float* xo = x2f + (size_t)t * 512 + d0;
  bf16* xb = x2b + (size_t)t * 512 + d0;
  for (int u = 0; u < 8; ++u) { xo[u] = v[u]; xb[u] = __float2bfloat16(v[u]); }
  float p[8];
  for (int ee = 0; ee < 8; ++ee) p[ee] = 0.f;
  for (int u = 0; u < 8; ++u) {
    float4 g0 = *(const float4*)(Wg + (size_t)(d0 + u) * 8);
    float4 g1 = *(const float4*)(Wg + (size_t)(d0 + u) * 8 + 4);
    p[0] += v[u] * g0.x; p[1] += v[u] * g0.y; p[2] += v[u] * g0.z; p[3] += v[u] * g0.w;
    p[4] += v[u] * g1.x; p[5] += v[u] * g1.y; p[6] += v[u] * g1.z; p[7] += v[u] * g1.w;
  }
  for (int o = 32; o > 0; o >>= 1)
    for (int ee = 0; ee < 8; ++ee) p[ee] += __shfl_xor(p[ee], o);
  if (lane == 0) {
    float mx = -1e30f;
    for (int ee = 0; ee < 8; ++ee) mx = fmaxf(mx, p[ee]);
    for (int ee = 0; ee < 8; ++ee) p[ee] = __expf(p[ee] - mx);
    int i1 = 0; float v1 = p[0];
    for (int ee = 1; ee < 8; ++ee) if (p[ee] > v1) { v1 = p[ee]; i1 = ee; }
    int i2 = -1; float v2 = -1.f;
    for (int ee = 0; ee < 8; ++ee) if (ee != i1 && p[ee] > v2) { v2 = p[ee]; i2 = ee; }
    float ws = v1 + v2;
    tokexp[t * 2] = i1; tokexp[t * 2 + 1] = i2;
    tokgate[t * 2] = v1 / ws; tokgate[t * 2 + 1] = v2 / ws;
  }
}

// ---------------- count: LDS histogram, 8 global atomics per block ----------------
__global__ __launch_bounds__(256) void k_count(const int* __restrict__ tokexp,
                                               int* __restrict__ counts) {
  __shared__ int lc[8];
  if (threadIdx.x < 8) lc[threadIdx.x] = 0;
  __syncthreads();
  int i = blockIdx.x * 256 + threadIdx.x;
  atomicAdd(&lc[tokexp[i]], 1);
  __syncthreads();
  if (threadIdx.x < 8) atomicAdd(&counts[threadIdx.x], lc[threadIdx.x]);
}

// ---------------- MoE setup ----------------
__global__ __launch_bounds__(256) void k_moe_setup(const int* __restrict__ counts,
                                                   int* __restrict__ segstart,
                                                   int* __restrict__ tileexp,
                                                   int* __restrict__ rowtok) {
  __shared__ int ss[9], cc[8];
  if (threadIdx.x < 8) cc[threadIdx.x] = counts[threadIdx.x];
  __syncthreads();
  if (threadIdx.x == 0) {
    int off = 0;
    for (int e = 0; e < 8; ++e) { ss[e] = off; off += ((cc[e] + 127) >> 7) << 7; }
    ss[8] = off;
    for (int e = 0; e < 9; ++e) segstart[e] = ss[e];
  }
  __syncthreads();
  for (int tl = threadIdx.x; tl < NTILES; tl += 256) {
    int ex;
    if (tl >= 200) ex = 9;
    else if (tl >= 136) ex = 8;
    else {
      int row = tl * 128; ex = -1;
      for (int i = 0; i < 8; ++i)
        if (row >= ss[i] && row < ss[i + 1]) { ex = i; break; }
    }
    tileexp[tl] = ex;
  }
  for (int e = 0; e < 8; ++e) {
    int cnt = cc[e], cap = ((cnt + 127) >> 7) << 7;
    for (int r = cnt + threadIdx.x; r < cap; r += 256)
      rowtok[ss[e] + r] = -1;
  }
}

// ---------------- assign rows ----------------
__global__ __launch_bounds__(256) void k_assign(const int* __restrict__ tokexp,
                                                int* __restrict__ fill,
                                                const int* __restrict__ segstart,
                                                int* __restrict__ rowtok,
                                                int* __restrict__ tokslot) {
  __shared__ int lcnt[8], lbase[8];
  if (threadIdx.x < 8) lcnt[threadIdx.x] = 0;
  __syncthreads();
  int t = blockIdx.x * 256 + threadIdx.x;
  int e0 = tokexp[t * 2], e1 = tokexp[t * 2 + 1];
  int r0 = atomicAdd(&lcnt[e0], 1);
  int r1 = atomicAdd(&lcnt[e1], 1);
  __syncthreads();
  if (threadIdx.x < 8) lbase[threadIdx.x] = atomicAdd(&fill[threadIdx.x], lcnt[threadIdx.x]);
  __syncthreads();
  int p0 = segstart[e0] + lbase[e0] + r0;
  int p1 = segstart[e1] + lbase[e1] + r1;
  rowtok[p0] = t; rowtok[p1] = t;
  tokslot[t * 2] = p0; tokslot[t * 2 + 1] = p1;
  rowtok[SH0_ROW + t] = t;
  rowtok[SH1_ROW + t] = t;
}

// ---------------- combine ----------------
__global__ __launch_bounds__(256) void k_combine(const float* __restrict__ x2f,
                                                 const bf16* __restrict__ Yg,
                                                 const int* __restrict__ tokslot,
                                                 const float* __restrict__ tokgate,
                                                 float* __restrict__ out_x) {
  int t = blockIdx.x * 4 + (threadIdx.x >> 6);
  int lane = threadIdx.x & 63;
  int s1 = tokslot[t * 2], s2 = tokslot[t * 2 + 1];
  float g1 = tokgate[t * 2], g2 = tokgate[t * 2 + 1];
  int d0 = lane * 8;
  short8 a = *(const short8*)(Yg + (size_t)s1 * 512 + d0);
  short8 b = *(const short8*)(Yg + (size_t)s2 * 512 + d0);
  short8 c = *(const short8*)(Yg + (size_t)(SH0_ROW + t) * 512 + d0);
  short8 d = *(const short8*)(Yg + (size_t)(SH1_ROW + t) * 512 + d0);
  const float* xr = x2f + (size_t)t * 512 + d0;
  float* outr = out_x + (size_t)t * 512 + d0;
  for (int u = 0; u < 8; ++u)
    outr[u] = xr[u] + g1 * b2f(a[u]) + g2 * b2f(b[u]) + b2f(c[u]) + b2f(d[u]);
}

// ---------------- host ----------------
extern "C" void kernel_launch(void* const* d_in, const int* in_sizes, int n_in,
                              void* d_out, int out_size, void* d_ws, size_t ws_size,
                              hipStream_t stream) {
  const float* x    = (const float*)d_in[0];
  const float* n2w  = (const float*)d_in[1];
  const float* Wdq  = (const float*)d_in[2];
  const float* qnw  = (const float*)d_in[3];
  const float* Wuq  = (const float*)d_in[4];
  const float* Wdkv = (const float*)d_in[5];
  const float* kvnw = (const float*)d_in[6];
  const float* Wukv = (const float*)d_in[7];
  const float* Wo   = (const float*)d_in[8];
  const float* Wg   = (const float*)d_in[9];
  const float* We1  = (const float*)d_in[10];
  const float* We2  = (const float*)d_in[11];
  const float* Ws1  = (const float*)d_in[12];
  const float* Ws2  = (const float*)d_in[13];

  float* out_x  = (float*)d_out;
  float* out_kv = out_x + (size_t)4 * 2048 * 512;

  char* base = (char*)d_ws;
  size_t off = 0;
  auto alloc = [&](size_t bytes) -> void* {
    void* p = base + off;
    off += (bytes + 255) & ~(size_t)255;
    return p;
  };
  const size_t T = 8192;
  // ---- persistent region ----
  bf16*  WcatT = (bf16*)alloc(352 * 512 * 2);
  bf16*  WuqT  = (bf16*)alloc(384 * 192 * 2);
  bf16*  WukvT = (bf16*)alloc(768 * 128 * 2);
  bf16*  WoT   = (bf16*)alloc(512 * 512 * 2);
  bf16*  W1T   = (bf16*)alloc((size_t)10 * 1024 * 512 * 2);
  bf16*  W2T   = (bf16*)alloc((size_t)10 * 512 * 1024 * 2);
  float* x2f   = (float*)alloc(T * 512 * 4);
  bf16*  x2b   = (bf16*)alloc(T * 512 * 2);
  int*   tokexp  = (int*)alloc(T * 2 * 4);
  float* tokgate = (float*)alloc(T * 2 * 4);
  int*   tokslot = (int*)alloc(T * 2 * 4);
  int*   rowtok  = (int*)alloc(ROWCAP * 4);
  int*   segstart= (int*)alloc(16 * 4);
  int*   tileexp = (int*)alloc(NTILES * 4);
  int*   cnts    = (int*)alloc(16 * 4);
  float* ropet   = (float*)alloc(2048 * 32 * 4);

  // ---- scratch region (NO aliasing; MoE phase reuses S from the top) ----
  char* S = base + off;
  size_t soff = 0;
  auto salloc = [&](size_t bytes) -> void* {
    void* p = S + soff;
    soff += (bytes + 255) & ~(size_t)255;
    return p;
  };
  bf16*  xb    = (bf16*)salloc(T * 512 * 2);
  float* tmp0  = (float*)salloc(T * 352 * 4);
  bf16*  cq    = (bf16*)salloc(T * 192 * 2);
  bf16*  kvn   = (bf16*)salloc(T * 128 * 2);
  float* krope = (float*)salloc(T * 32 * 4);
  bf16*  kvbig = (bf16*)salloc(T * 768 * 2);
  bf16*  qf    = (bf16*)salloc(T * 384 * 2);
  bf16*  kf    = (bf16*)salloc(T * 384 * 2);
  bf16*  vT    = (bf16*)salloc(T * 512 * 2);
  bf16*  attnb = (bf16*)salloc(T * 512 * 2);
  bf16*  woout = (bf16*)salloc(T * 512 * 2);
  bf16*  pO    = (bf16*)salloc((size_t)16 * NPART * 4096 * 2);  // 36.7 MB
  float* pML   = (float*)salloc((size_t)16 * NPART * 64 * 4);
  size_t attn_ws = soff;
  bf16* Hg = (bf16*)S;
  bf16* Yg = (bf16*)(S + (size_t)ROWCAP * 1024 * 2 + 256);
  size_t moe_ws = (size_t)ROWCAP * 1024 * 2 + 256 + (size_t)ROWCAP * 512 * 2;
  size_t need = off + (attn_ws > moe_ws ? attn_ws : moe_ws);
  if (need > ws_size) return;

  hipMemsetAsync(cnts, 0, 64, stream);

  // x -> bf16 ; rope table
  k_f32_to_bf16<<<(int)((T * 512 + 255) / 256), 256, 0, stream>>>(x, xb, (int)(T * 512));
  k_rope_table<<<128, 256, 0, stream>>>(ropet);

  // all weight transposes in ONE kernel
  {
    Tall TT;
    auto mk = [](const float* s, bf16* d, int K, int N, int ldo, int nz,
                 long inZ, long outZ, int start) -> TD {
      TD t; t.src = s; t.dst = d; t.K = K; t.N = N; t.ldo = ldo;
      t.bx = (K + 63) / 64; t.bxy = t.bx * ((N + 63) / 64);
      t.start = start; t.inZ = inZ; t.outZ = outZ; (void)nz; return t;
    };
    int st = 0;
    TT.d[0] = mk(Wdq,  WcatT,             512, 192, 512, 1, 0, 0, st); st += 24;
    TT.d[1] = mk(Wdkv, WcatT + 192 * 512, 512, 160, 512, 1, 0, 0, st); st += 24;
    TT.d[2] = mk(Wuq,  WuqT,  192, 384, 192, 1, 0, 0, st); st += 18;
    TT.d[3] = mk(Wukv, WukvT, 128, 768, 128, 1, 0, 0, st); st += 24;
    TT.d[4] = mk(Wo,   WoT,   512, 512, 512, 1, 0, 0, st); st += 64;
    TT.d[5] = mk(We1, W1T, 512, 1024, 512, 8, (long)512 * 1024, (long)1024 * 512, st); st += 1024;
    TT.d[6] = mk(Ws1, W1T + (size_t)8 * 1024 * 512, 512, 1024, 512, 2,
                 (long)512 * 1024, (long)1024 * 512, st); st += 256;
    TT.d[7] = mk(We2, W2T, 1024, 512, 1024, 8, (long)1024 * 512, (long)512 * 1024, st); st += 1024;
    TT.d[8] = mk(Ws2, W2T + (size_t)8 * 512 * 1024, 1024, 512, 1024, 2,
                 (long)1024 * 512, (long)512 * 1024, st); st += 256;
    k_transpose_all<<<st, 256, 0, stream>>>(TT);
  }

  // x @ [W_dq | W_dkv] -> tmp0 (f32), then norms/splits (+ f32 kv output)
  k_gemm_dq<<<dim3(64, 3), 256, 0, stream>>>(xb, WcatT, 352, 512, 512, 512, 352, tmp0);
  k_postproj1<<<2048, 256, 0, stream>>>(tmp0, qnw, kvnw, cq, kvn, krope, out_kv);

  // q path: GEMM with fused rope -> qf directly
  k_gemm_q<<<dim3(64, 3), 256, 0, stream>>>(cq, WuqT, ropet, qf);

  // kv path
  k_gemm_kv<<<dim3(64, 6), 256, 0, stream>>>(kvn, WukvT, 768, 128, 128, 128, 768, kvbig);
  k_make_kf<<<12288, 256, 0, stream>>>(kvbig, krope, ropet, kf);
  k_make_vT<<<dim3(32, 16), 256, 0, stream>>>(kvbig, vT);

  // attention: 1D grid with bh-per-XCD locality + merge (bands 1-7)
  k_flash<<<NCHUNK * 16, 64, 0, stream>>>(qf, kf, vT, attnb, pO, pML);
  k_merge<<<dim3(56, 16), 512, 0, stream>>>(pO, pML, attnb);

  // W_o (bf16 out), fused residual+norm2+gating
  k_gemm_wo<<<dim3(64, 4), 256, 0, stream>>>(attnb, WoT, 512, 512, 512, 512, 512, woout);
  k_norm2g<<<2048, 256, 0, stream>>>(x, woout, n2w, Wg, x2f, x2b, tokexp, tokgate);
  k_count<<<64, 256, 0, stream>>>(tokexp, cnts);
  k_moe_setup<<<1, 256, 0, stream>>>(cnts, segstart, tileexp, rowtok);
  k_assign<<<32, 256, 0, stream>>>(tokexp, cnts + 8, segstart, rowtok, tokslot);

  // sparse MoE: grouped up (silu) -> grouped down -> combine (XCD tile slices)
  k_gemm_grouped<1><<<dim3(NTILES, 8), 256, 0, stream>>>(
      x2b, rowtok, tileexp, W1T, (size_t)1024 * 512, 1024, 512, 512, Hg, 1024);
  k_gemm_grouped<0><<<dim3(NTILES, 4), 256, 0, stream>>>(
      Hg, nullptr, tileexp, W2T, (size_t)512 * 1024, 512, 1024, 1024, Yg, 512);
  k_combine<<<2048, 256, 0, stream>>>(x2f, Yg, tokslot, tokgate, out_x);
}

// Round 19
// 343.000 us; speedup vs baseline: 1.0265x; 1.0265x over previous
//
#include <hip/hip_runtime.h>
#include <hip/hip_bf16.h>

typedef __hip_bfloat16 bf16;
typedef __attribute__((ext_vector_type(8))) short short8;
typedef __attribute__((ext_vector_type(8))) __bf16 bf16x8;
typedef __attribute__((ext_vector_type(4))) float f32x4;

#define RT_ROWS 17408
#define SH0_ROW 17408
#define SH1_ROW 25600
#define ROWCAP  33792
#define NTILES  264
#define NCHUNK  288     // flash chunks per bh (Q-blocks of 32 rows, bands 8x{1..8})
#define NPART   280     // chunks that write partials (bands 1-7)

static __device__ __forceinline__ f32x4 mfma16(short8 a, short8 b, f32x4 c) {
  return __builtin_amdgcn_mfma_f32_16x16x32_bf16(
      __builtin_bit_cast(bf16x8, a), __builtin_bit_cast(bf16x8, b), c, 0, 0, 0);
}

static __device__ __forceinline__ void gload16(const bf16* g, void* l) {
  __builtin_amdgcn_global_load_lds(
      (const __attribute__((address_space(1))) void*)g,
      (__attribute__((address_space(3))) void*)l, 16, 0, 0);
}

static __device__ __forceinline__ float b2f(short s) {
  unsigned u = ((unsigned)(unsigned short)s) << 16;
  return __builtin_bit_cast(float, u);
}

// ---------------- elementwise f32 -> bf16 ----------------
__global__ __launch_bounds__(256) void k_f32_to_bf16(const float* __restrict__ in,
                                                     bf16* __restrict__ out, int n) {
  int i = blockIdx.x * 256 + threadIdx.x;
  if (i < n) out[i] = __float2bfloat16(in[i]);
}

// ---------------- ALL weight transposes in one kernel ----------------
struct TD { const float* src; bf16* dst; int K, N, ldo, bx, bxy, start; long inZ, outZ; };
struct Tall { TD d[9]; };

__global__ __launch_bounds__(256) void k_transpose_all(Tall T) {
  int gid = blockIdx.x;
  int si = 0;
  #pragma unroll
  for (int i = 1; i < 9; ++i)
    if (gid >= T.d[i].start) si = i;
  TD dd = T.d[si];
  int local = gid - dd.start;
  int z = local / dd.bxy, rem = local - z * dd.bxy;
  int k0 = (rem % dd.bx) * 64, n0 = (rem / dd.bx) * 64;
  const float* in = dd.src + (size_t)z * dd.inZ;
  bf16* out = dd.dst + (size_t)z * dd.outZ;
  __shared__ bf16 t[64][65];
  for (int rep = 0; rep < 16; ++rep) {
    int lin = rep * 256 + threadIdx.x;
    int i = lin >> 6, j = lin & 63;
    if (k0 + i < dd.K && n0 + j < dd.N)
      t[i][j] = __float2bfloat16(in[(size_t)(k0 + i) * dd.N + n0 + j]);
  }
  __syncthreads();
  for (int rep = 0; rep < 16; ++rep) {
    int lin = rep * 256 + threadIdx.x;
    int jj = lin >> 6, ii = lin & 63;
    if (n0 + jj < dd.N && k0 + ii < dd.K)
      out[(size_t)(n0 + jj) * dd.ldo + k0 + ii] = t[ii][jj];
  }
}

// ---------------- shared dense NT GEMM core ----------------
static __device__ __forceinline__ void gemm_core(
    const bf16* __restrict__ A, const bf16* __restrict__ BT,
    int N, int K, int lda, int ldb, int ldc,
    float* __restrict__ Cf, bf16* __restrict__ Cb) {
  __shared__ __align__(16) bf16 As[128 * 32];
  __shared__ __align__(16) bf16 Bs[128 * 32];
  const int m0 = blockIdx.x * 128, n0 = blockIdx.y * 128;
  const int tid = threadIdx.x, lane = tid & 63, wave = tid >> 6;
  const int wr = (wave >> 1) * 64, wc = (wave & 1) * 64;
  const int lr = lane & 15;
  const int kgs = (((lane >> 4) ^ ((lane >> 1) & 3)) << 3);
  const int srow = wave * 16 + (lane >> 2);
  const int scol = (((lane & 3) ^ ((lane >> 3) & 3)) << 3);
  const bf16* Ab = A + (size_t)(m0 + srow) * lda + scol;
  const bf16* Bb = BT + (size_t)(n0 + srow) * ldb + scol;
  char* AsL = (char*)As + wave * 1024;
  char* BsL = (char*)Bs + wave * 1024;

  f32x4 acc[4][4];
  for (int i = 0; i < 4; ++i)
    for (int j = 0; j < 4; ++j) acc[i][j] = f32x4{0.f, 0.f, 0.f, 0.f};

  for (int k0 = 0; k0 < K; k0 += 32) {
    __syncthreads();
    gload16(Ab + k0, AsL);
    gload16(Ab + (size_t)64 * lda + k0, AsL + 4096);
    gload16(Bb + k0, BsL);
    gload16(Bb + (size_t)64 * ldb + k0, BsL + 4096);
    __syncthreads();
    short8 af[4], bfr[4];
    for (int i = 0; i < 4; ++i) af[i] = *(const short8*)&As[(wr + i * 16 + lr) * 32 + kgs];
    for (int j = 0; j < 4; ++j) bfr[j] = *(const short8*)&Bs[(wc + j * 16 + lr) * 32 + kgs];
    for (int i = 0; i < 4; ++i)
      for (int j = 0; j < 4; ++j)
        acc[i][j] = mfma16(af[i], bfr[j], acc[i][j]);
  }

  for (int i = 0; i < 4; ++i) {
    int mb = m0 + wr + i * 16 + (lane >> 4) * 4;
    for (int j = 0; j < 4; ++j) {
      int n = n0 + wc + j * 16 + lr;
      if (n >= N) continue;
      for (int r = 0; r < 4; ++r) {
        size_t idx = (size_t)(mb + r) * ldc + n;
        float v = acc[i][j][r];
        if (Cf) Cf[idx] = v;
        else Cb[idx] = __float2bfloat16(v);
      }
    }
  }
}

__global__ __launch_bounds__(256) void k_gemm_dq(
    const bf16* A, const bf16* BT, int N, int K, int lda, int ldb, int ldc, float* Cf) {
  gemm_core(A, BT, N, K, lda, ldb, ldc, Cf, nullptr);
}
__global__ __launch_bounds__(256) void k_gemm_kv(
    const bf16* A, const bf16* BT, int N, int K, int lda, int ldb, int ldc, bf16* Cb) {
  gemm_core(A, BT, N, K, lda, ldb, ldc, nullptr, Cb);
}
__global__ __launch_bounds__(256) void k_gemm_wo(
    const bf16* A, const bf16* BT, int N, int K, int lda, int ldb, int ldc, bf16* Cb) {
  gemm_core(A, BT, N, K, lda, ldb, ldc, nullptr, Cb);
}

// ---------------- q-projection GEMM with FUSED rope epilogue -> qf ---------------
__global__ __launch_bounds__(256) void k_gemm_q(
    const bf16* __restrict__ A, const bf16* __restrict__ BT,
    const float* __restrict__ tab, bf16* __restrict__ qf) {
  const int K = 192, lda = 192, ldb = 192;
  __shared__ __align__(16) bf16 As[128 * 32];
  __shared__ __align__(16) bf16 Bs[128 * 32];
  const int m0 = blockIdx.x * 128, n0 = blockIdx.y * 128;
  const int tid = threadIdx.x, lane = tid & 63, wave = tid >> 6;
  const int wr = (wave >> 1) * 64, wc = (wave & 1) * 64;
  const int lr = lane & 15;
  const int kgs = (((lane >> 4) ^ ((lane >> 1) & 3)) << 3);
  const int srow = wave * 16 + (lane >> 2);
  const int scol = (((lane & 3) ^ ((lane >> 3) & 3)) << 3);
  const bf16* Ab = A + (size_t)(m0 + srow) * lda + scol;
  const bf16* Bb = BT + (size_t)(n0 + srow) * ldb + scol;
  char* AsL = (char*)As + wave * 1024;
  char* BsL = (char*)Bs + wave * 1024;

  f32x4 acc[4][4];
  for (int i = 0; i < 4; ++i)
    for (int j = 0; j < 4; ++j) acc[i][j] = f32x4{0.f, 0.f, 0.f, 0.f};

  for (int k0 = 0; k0 < K; k0 += 32) {
    __syncthreads();
    gload16(Ab + k0, AsL);
    gload16(Ab + (size_t)64 * lda + k0, AsL + 4096);
    gload16(Bb + k0, BsL);
    gload16(Bb + (size_t)64 * ldb + k0, BsL + 4096);
    __syncthreads();
    short8 af[4], bfr[4];
    for (int i = 0; i < 4; ++i) af[i] = *(const short8*)&As[(wr + i * 16 + lr) * 32 + kgs];
    for (int j = 0; j < 4; ++j) bfr[j] = *(const short8*)&Bs[(wc + j * 16 + lr) * 32 + kgs];
    for (int i = 0; i < 4; ++i)
      for (int j = 0; j < 4; ++j)
        acc[i][j] = mfma16(af[i], bfr[j], acc[i][j]);
  }

  #pragma unroll
  for (int i = 0; i < 4; ++i) {
    int mb = m0 + wr + i * 16 + (lane >> 4) * 4;
    #pragma unroll
    for (int j = 0; j < 4; ++j) {
      int n = n0 + wc + j * 16 + lr;
      int h = (n >= 288) ? 3 : ((n >= 192) ? 2 : ((n >= 96) ? 1 : 0));
      int d = n - h * 96;
      #pragma unroll
      for (int r = 0; r < 4; ++r) {
        int t = mb + r;
        int s = t & 2047;
        float v;
        if (d < 64) {
          v = acc[i][j][r];
        } else {
          float c = tab[s * 32 + lr], sn = tab[s * 32 + 16 + lr];
          if (d < 80) {
            float x1 = acc[i][j][r];
            float x2 = (j < 3) ? acc[i][j + 1][r] : 0.f;
            v = x1 * c - x2 * sn;
          } else {
            float x1 = (j > 0) ? acc[i][j - 1][r] : 0.f;
            float x2 = acc[i][j][r];
            v = x2 * c + x1 * sn;
          }
        }
        size_t bh = (size_t)(t >> 11) * 4 + h;
        qf[bh * (2048 * 96) + (size_t)s * 96 + d] = __float2bfloat16(v);
      }
    }
  }
}

// ---------------- grouped expert GEMM: 3-buffer depth-2 counted-vmcnt pipeline ----
// T4 recipe: loads span TWO compute phases; vmcnt(4) in steady state (tile i+1
// landed, tile i+2's 4 loads stay in flight); drain vmcnt(0) only at the tail.
template <int ACT>
__global__ __launch_bounds__(256) void k_gemm_grouped(
    const bf16* __restrict__ A, const int* __restrict__ rowtok,
    const int* __restrict__ tileexp, const bf16* __restrict__ W, size_t wstride,
    int N, int K, int lda, bf16* __restrict__ out, int ldo) {
  int bx = (int)blockIdx.x;
  const int tl = (bx & 7) * 33 + (bx >> 3);   // XCD x owns tiles [33x, 33x+33)
  const int ex = tileexp[tl];
  if (ex < 0) return;
  __shared__ __align__(16) bf16 As[3][128 * 32];   // 24 KB
  __shared__ __align__(16) bf16 Bs[3][128 * 32];   // 24 KB
  const int m0 = tl * 128, n0 = blockIdx.y * 128;
  const int tid = threadIdx.x, lane = tid & 63, wave = tid >> 6;
  const int wr = (wave >> 1) * 64, wc = (wave & 1) * 64;
  const int lr = lane & 15;
  const int kgs = (((lane >> 4) ^ ((lane >> 1) & 3)) << 3);
  const int srow = wave * 16 + (lane >> 2);
  const int scol = (((lane & 3) ^ ((lane >> 3) & 3)) << 3);

  int ar0 = m0 + srow, ar1 = ar0 + 64;
  if (rowtok) {
    int t0 = rowtok[ar0]; ar0 = (t0 < 0) ? 0 : t0;
    int t1 = rowtok[ar1]; ar1 = (t1 < 0) ? 0 : t1;
  }
  const bf16* A0 = A + (size_t)ar0 * lda + scol;
  const bf16* A1 = A + (size_t)ar1 * lda + scol;
  const bf16* BT = W + (size_t)ex * wstride;
  const bf16* B0 = BT + (size_t)(n0 + srow) * K + scol;
  const bf16* B1 = B0 + (size_t)64 * K;

  auto stage = [&](int buf, int k0) {
    char* AsL = (char*)As[buf] + wave * 1024;
    char* BsL = (char*)Bs[buf] + wave * 1024;
    gload16(A0 + k0, AsL);
    gload16(A1 + k0, AsL + 4096);
    gload16(B0 + k0, BsL);
    gload16(B1 + k0, BsL + 4096);
  };

  f32x4 acc[4][4];
  for (int i = 0; i < 4; ++i)
    for (int j = 0; j < 4; ++j) acc[i][j] = f32x4{0.f, 0.f, 0.f, 0.f};

  const int nIter = K >> 5;  // K/32 (16 or 32)
  // prologue: tiles 0 and 1 in flight; wait tile 0 only (oldest 4 loads)
  stage(0, 0);
  stage(1, 32);
  asm volatile("s_waitcnt vmcnt(4)" ::: "memory");
  __builtin_amdgcn_s_barrier();

  int cur = 0, stg = 2;
  for (int i = 0; i < nIter; ++i) {
    if (i + 2 < nIter) stage(stg, (i + 2) * 32);  // into buffer vacated by tile i-1
    short8 af[4], bfr[4];
    #pragma unroll
    for (int ii = 0; ii < 4; ++ii)
      af[ii] = *(const short8*)&As[cur][(wr + ii * 16 + lr) * 32 + kgs];
    #pragma unroll
    for (int jj = 0; jj < 4; ++jj)
      bfr[jj] = *(const short8*)&Bs[cur][(wc + jj * 16 + lr) * 32 + kgs];
    #pragma unroll
    for (int ii = 0; ii < 4; ++ii)
      #pragma unroll
      for (int jj = 0; jj < 4; ++jj)
        acc[ii][jj] = mfma16(af[ii], bfr[jj], acc[ii][jj]);
    if (i + 2 < nIter) {
      asm volatile("s_waitcnt vmcnt(4)" ::: "memory");   // tile i+1 landed; i+2 flying
      __builtin_amdgcn_s_barrier();
    } else if (i + 1 < nIter) {
      asm volatile("s_waitcnt vmcnt(0)" ::: "memory");   // tail drain
      __builtin_amdgcn_s_barrier();
    }
    if (++cur == 3) cur = 0;
    if (++stg == 3) stg = 0;
  }

  for (int i = 0; i < 4; ++i) {
    int mb = m0 + wr + i * 16 + (lane >> 4) * 4;
    for (int j = 0; j < 4; ++j) {
      int n = n0 + wc + j * 16 + lr;
      for (int r = 0; r < 4; ++r) {
        float v = acc[i][j][r];
        if (ACT) v = v / (1.f + __expf(-v));
        out[(size_t)(mb + r) * ldo + n] = __float2bfloat16(v);
      }
    }
  }
}

// ---------------- post GEMM0: rmsnorms + split, write kv output (f32) ----------------
__global__ __launch_bounds__(256) void k_postproj1(
    const float* __restrict__ tmp, const float* __restrict__ qnw,
    const float* __restrict__ kvnw, bf16* __restrict__ cq,
    bf16* __restrict__ kvn, float* __restrict__ krope, float* __restrict__ kvout) {
  int t = blockIdx.x * 4 + (threadIdx.x >> 6);
  int lane = threadIdx.x & 63;
  const float* row = tmp + (size_t)t * 352;
  float s1 = 0.f, s2 = 0.f;
  for (int d = lane; d < 192; d += 64) { float v = row[d]; s1 += v * v; }
  for (int d = lane; d < 128; d += 64) { float v = row[192 + d]; s2 += v * v; }
  for (int o = 32; o > 0; o >>= 1) { s1 += __shfl_xor(s1, o); s2 += __shfl_xor(s2, o); }
  float r1 = rsqrtf(s1 / 192.f + 1e-6f);
  float r2 = rsqrtf(s2 / 128.f + 1e-6f);
  for (int d = lane; d < 192; d += 64)
    cq[(size_t)t * 192 + d] = __float2bfloat16(row[d] * r1 * qnw[d]);
  for (int d = lane; d < 128; d += 64)
    kvn[(size_t)t * 128 + d] = __float2bfloat16(row[192 + d] * r2 * kvnw[d]);
  for (int d = lane; d < 160; d += 64)
    kvout[(size_t)t * 160 + d] = row[192 + d];
  if (lane < 32) krope[(size_t)t * 32 + lane] = row[320 + lane];
}

// ---------------- rope cos/sin table ----------------
__global__ __launch_bounds__(256) void k_rope_table(float* __restrict__ tab) {
  int idx = blockIdx.x * 256 + threadIdx.x;  // 2048*16
  int s = idx >> 4, jm = idx & 15;
  float invf = expf(-(float)jm * 0.575646273f);
  float ang = (float)s * invf;
  tab[s * 32 + jm] = cosf(ang);
  tab[s * 32 + 16 + jm] = sinf(ang);
}

// ---------------- k: nope copy + shared roped k_rope ----------------
__global__ __launch_bounds__(256) void k_make_kf(const bf16* __restrict__ kvbig,
                                                 const float* __restrict__ krope,
                                                 const float* __restrict__ tab,
                                                 bf16* __restrict__ kf) {
  int idx = blockIdx.x * 256 + threadIdx.x;
  int t = idx / 384, hd = idx - t * 384;
  int h = hd / 96, d = hd - h * 96;
  int s = t & 2047;
  bf16 outv;
  if (d < 64) outv = kvbig[(size_t)t * 768 + h * 192 + d];
  else {
    int j = d - 64, jm = j & 15;
    float c = tab[s * 32 + jm], sn = tab[s * 32 + 16 + jm];
    float x1 = krope[(size_t)t * 32 + jm], x2 = krope[(size_t)t * 32 + 16 + jm];
    float v = (j < 16) ? (x1 * c - x2 * sn) : (x2 * c + x1 * sn);
    outv = __float2bfloat16(v);
  }
  size_t bh = (size_t)(t >> 11) * 4 + h;
  kf[bh * (2048 * 96) + (size_t)s * 96 + d] = outv;
}

// ---------------- v: extract + transpose to [bh][d=128][s=2048] ----------------
__global__ __launch_bounds__(256) void k_make_vT(const bf16* __restrict__ kvbig,
                                                 bf16* __restrict__ vT) {
  __shared__ bf16 t[64][136];
  int bh = blockIdx.y;
  int b = bh >> 2, h = bh & 3;
  int s0 = blockIdx.x * 64;
  for (int rep = 0; rep < 4; ++rep) {
    int lin = rep * 256 + threadIdx.x;
    int i = lin >> 4, jc = (lin & 15) * 8;
    short8 v = *(const short8*)(kvbig + (size_t)(b * 2048 + s0 + i) * 768 + h * 192 + 64 + jc);
    *(short8*)&t[i][jc] = v;
  }
  __syncthreads();
  for (int rep = 0; rep < 32; ++rep) {
    int lin = rep * 256 + threadIdx.x;
    int d = lin >> 6, i = lin & 63;
    vT[((size_t)bh * 128 + d) * 2048 + s0 + i] = t[i][d];
  }
}

// ---------------- flash attention: 1D grid 4608, bh-per-XCD locality -------------
__global__ __launch_bounds__(64, 2) void k_flash(const bf16* __restrict__ qf,
                                                 const bf16* __restrict__ kf,
                                                 const bf16* __restrict__ vT,
                                                 bf16* __restrict__ attn,
                                                 bf16* __restrict__ pO,
                                                 float* __restrict__ pML) {
  const int lin = (int)blockIdx.x;
  const int r16 = lin & 15;
  const int bh = ((r16 & 7) << 1) | (r16 >> 3);
  const int e = (NCHUNK - 1) - (lin >> 4);   // big-band chunks dispatch first
  int k = 0;
  #pragma unroll
  for (int kk = 1; kk < 8; ++kk)
    if (e >= 4 * kk * (kk + 1)) k = kk;
  const int rel = e - 4 * k * (k + 1);
  const int Q = 8 * k + rel / (k + 1);
  const int c = rel - (rel / (k + 1)) * (k + 1);
  const int nt = (Q >> 1) + 1;
  const int kt0 = 4 * c;
  const int kt1 = (kt0 + 4 < nt) ? kt0 + 4 : nt;
  const int q0 = Q * 32;
  const int lane = threadIdx.x;
  const int lr = lane & 15, hi = lane >> 4, kg = hi * 8;
  const bf16* Qp = qf + (size_t)bh * (2048 * 96);
  const bf16* Kp = kf + (size_t)bh * (2048 * 96);
  const bf16* Vt = vT + (size_t)bh * (128 * 2048);

  short8 qfr[2][3];
  for (int i = 0; i < 2; ++i)
    for (int ks = 0; ks < 3; ++ks)
      qfr[i][ks] = *(const short8*)(Qp + (size_t)(q0 + i * 16 + lr) * 96 + ks * 32 + kg);

  f32x4 o[2][8];
  for (int i = 0; i < 2; ++i)
    for (int j = 0; j < 8; ++j) o[i][j] = f32x4{0.f, 0.f, 0.f, 0.f};
  float mrow[2][4], lsum[2][4];
  for (int i = 0; i < 2; ++i)
    for (int r = 0; r < 4; ++r) { mrow[i][r] = -1e30f; lsum[i][r] = 0.f; }

  __shared__ bf16 plds[32][72];
  const float scale = 0.1020620726f;  // 1/sqrt(96)

  for (int kt = kt0; kt < kt1; ++kt) {
    int kv0 = kt * 64;
    f32x4 s[2][4];
    for (int i = 0; i < 2; ++i)
      for (int j = 0; j < 4; ++j) s[i][j] = f32x4{0.f, 0.f, 0.f, 0.f};
    for (int jh = 0; jh < 2; ++jh) {
      short8 kc[2][3];
      for (int jj = 0; jj < 2; ++jj)
        for (int ks = 0; ks < 3; ++ks)
          kc[jj][ks] = *(const short8*)(Kp + (size_t)(kv0 + (jh * 2 + jj) * 16 + lr) * 96 + ks * 32 + kg);
      for (int jj = 0; jj < 2; ++jj)
        for (int ks = 0; ks < 3; ++ks) {
          s[0][jh * 2 + jj] = mfma16(qfr[0][ks], kc[jj][ks], s[0][jh * 2 + jj]);
          s[1][jh * 2 + jj] = mfma16(qfr[1][ks], kc[jj][ks], s[1][jh * 2 + jj]);
        }
    }

    bool diag = (kt == nt - 1);
    for (int i = 0; i < 2; ++i)
      for (int j = 0; j < 4; ++j)
        for (int r = 0; r < 4; ++r) {
          float v = s[i][j][r] * scale;
          if (diag) {
            int qq = q0 + i * 16 + hi * 4 + r;
            int kk = kv0 + j * 16 + lr;
            if (kk > qq) v = -1e30f;
          }
          s[i][j][r] = v;
        }
    float vmax4[2][4], grow = -1e30f;
    for (int i = 0; i < 2; ++i)
      for (int r = 0; r < 4; ++r) {
        float v = fmaxf(fmaxf(s[i][0][r], s[i][1][r]), fmaxf(s[i][2][r], s[i][3][r]));
        v = fmaxf(v, __shfl_xor(v, 1));
        v = fmaxf(v, __shfl_xor(v, 2));
        v = fmaxf(v, __shfl_xor(v, 4));
        v = fmaxf(v, __shfl_xor(v, 8));
        vmax4[i][r] = v;
        grow = fmaxf(grow, v - mrow[i][r]);
      }
    if (!__all(grow <= 8.f)) {
      for (int i = 0; i < 2; ++i)
        for (int r = 0; r < 4; ++r) {
          float mnew = fmaxf(mrow[i][r], vmax4[i][r]);
          float alpha = __expf(mrow[i][r] - mnew);
          mrow[i][r] = mnew;
          lsum[i][r] *= alpha;
          for (int j = 0; j < 8; ++j) o[i][j][r] *= alpha;
        }
    }
    for (int i = 0; i < 2; ++i)
      for (int r = 0; r < 4; ++r) {
        float rs = 0.f;
        for (int j = 0; j < 4; ++j) {
          float p = __expf(s[i][j][r] - mrow[i][r]);
          s[i][j][r] = p;
          rs += p;
        }
        rs += __shfl_xor(rs, 1); rs += __shfl_xor(rs, 2);
        rs += __shfl_xor(rs, 4); rs += __shfl_xor(rs, 8);
        lsum[i][r] += rs;
      }
    // P via wave-private LDS roundtrip (1 wave: in-order DS pipe, no barrier)
    for (int i = 0; i < 2; ++i)
      for (int j = 0; j < 4; ++j)
        for (int r = 0; r < 4; ++r)
          plds[i * 16 + hi * 4 + r][j * 16 + lr] = __float2bfloat16(s[i][j][r]);
    short8 pf[2][2];
    for (int i = 0; i < 2; ++i) {
      pf[i][0] = *(const short8*)&plds[i * 16 + lr][kg];
      pf[i][1] = *(const short8*)&plds[i * 16 + lr][32 + kg];
    }
    for (int j = 0; j < 8; ++j) {
      short8 v0 = *(const short8*)(Vt + (size_t)(j * 16 + lr) * 2048 + kv0 + kg);
      short8 v1 = *(const short8*)(Vt + (size_t)(j * 16 + lr) * 2048 + kv0 + 32 + kg);
      o[0][j] = mfma16(pf[0][0], v0, o[0][j]);
      o[0][j] = mfma16(pf[0][1], v1, o[0][j]);
      o[1][j] = mfma16(pf[1][0], v0, o[1][j]);
      o[1][j] = mfma16(pf[1][1], v1, o[1][j]);
    }
  }

  if (k == 0) {
    int bb = bh >> 2, h = bh & 3;
    for (int i = 0; i < 2; ++i)
      for (int r = 0; r < 4; ++r) {
        int qq = q0 + i * 16 + hi * 4 + r;
        float inv = 1.f / lsum[i][r];
        size_t baseo = ((size_t)(bb * 2048 + qq)) * 512 + h * 128;
        for (int j = 0; j < 8; ++j)
          attn[baseo + j * 16 + lr] = __float2bfloat16(o[i][j][r] * inv);
      }
  } else {
    const int p = bh * NPART + (e - 8);
    for (int i = 0; i < 2; ++i)
      for (int r = 0; r < 4; ++r) {
        int qrl = i * 16 + hi * 4 + r;
        size_t baseo = (size_t)p * 4096 + (size_t)qrl * 128;
        for (int j = 0; j < 8; ++j)
          pO[baseo + j * 16 + lr] = __float2bfloat16(o[i][j][r]);
        if (lr == 0) {
          pML[p * 64 + qrl] = mrow[i][r];
          pML[p * 64 + 32 + qrl] = lsum[i][r];
        }
      }
  }
}

// ---------------- merge 2..8 partials per Q-block (bands 1-7) ----------------
__global__ __launch_bounds__(512) void k_merge(const bf16* __restrict__ pO,
                                               const float* __restrict__ pML,
                                               bf16* __restrict__ attn) {
  const int Q = 8 + blockIdx.x;  // 8..63
  const int bh = blockIdx.y;
  const int k = Q >> 3, np = k + 1;
  const int eb = 4 * k * (k + 1) + (Q - 8 * k) * (k + 1);
  const int pbase = bh * NPART + (eb - 8);
  const int qrl = threadIdx.x >> 4, d0 = (threadIdx.x & 15) * 8;
  float m[8], l[8], w[8];
  float mm = -1e30f;
  for (int i = 0; i < 8; ++i)
    if (i < np) {
      m[i] = pML[(pbase + i) * 64 + qrl];
      l[i] = pML[(pbase + i) * 64 + 32 + qrl];
      mm = fmaxf(mm, m[i]);
    }
  float L = 0.f;
  for (int i = 0; i < 8; ++i)
    if (i < np) { w[i] = __expf(m[i] - mm); L += l[i] * w[i]; }
  float inv = 1.f / L;
  float acc[8];
  for (int u = 0; u < 8; ++u) acc[u] = 0.f;
  for (int i = 0; i < 8; ++i)
    if (i < np) {
      short8 v = *(const short8*)(pO + (size_t)(pbase + i) * 4096 + (size_t)qrl * 128 + d0);
      for (int u = 0; u < 8; ++u) acc[u] += b2f(v[u]) * w[i];
    }
  int bb = bh >> 2, h = bh & 3;
  int q = Q * 32 + qrl;
  size_t ob = ((size_t)(bb * 2048 + q)) * 512 + h * 128 + d0;
  for (int u = 0; u < 8; ++u)
    attn[ob + u] = __float2bfloat16(acc[u] * inv);
}

// ---------------- fused residual + rmsnorm#2 + gating ----------------
__global__ __launch_bounds__(256) void k_norm2g(const float* __restrict__ x,
                                                const bf16* __restrict__ wo,
                                                const float* __restrict__ w,
                                                const float* __restrict__ Wg,
                                                float* __restrict__ x2f,
                                                bf16* __restrict__ x2b,
                                                int* __restrict__ tokexp,
                                                float* __restrict__ tokgate) {
  int wv = threadIdx.x >> 6, lane = threadIdx.x & 63;
  int t = blockIdx.x * 4 + wv;
  const float* row = x + (size_t)t * 512;
  int d0 = lane * 8;
  float v[8];
  {
    float4 a = *(const float4*)(row + d0);
    float4 bb = *(const float4*)(row + d0 + 4);
    short8 wv8 = *(const short8*)(wo + (size_t)t * 512 + d0);
    v[0] = a.x + b2f(wv8[0]); v[1] = a.y + b2f(wv8[1]);
    v[2] = a.z + b2f(wv8[2]); v[3] = a.w + b2f(wv8[3]);
    v[4] = bb.x + b2f(wv8[4]); v[5] = bb.y + b2f(wv8[5]);
    v[6] = bb.z + b2f(wv8[6]); v[7] = bb.w + b2f(wv8[7]);
  }
  float ss = 0.f;
  for (int u = 0; u < 8; ++u) ss += v[u] * v[u];
  for (int o = 32; o > 0; o >>= 1) ss += __shfl_xor(ss, o);
  float rr = rsqrtf(ss / 512.f + 1e-6f);
  {
    float4 a = *(const float4*)(w + d0);
    float4 bb = *(const float4*)(w + d0 + 4);
    v[0] *= rr * a.x; v[1] *= rr * a.y; v[2] *= rr * a.z; v[3] *= rr * a.w;
    v[4] *= rr * bb.x; v[5] *= rr * bb.y; v[6] *= rr * bb.z; v[7] *= rr * bb.w;
  }
  float* xo = x2f + (size_t)t * 512 + d0;
  bf16* xb = x2b + (size_t)t * 512 + d0;
  for (int u = 0; u < 8; ++u) { xo[u] = v[u]; xb[u] = __float2bfloat16(v[u]); }
  float p[8];
  for (int ee = 0; ee < 8; ++ee) p[ee] = 0.f;
  for (int u = 0; u < 8; ++u) {
    float4 g0 = *(const float4*)(Wg + (size_t)(d0 + u) * 8);
    float4 g1 = *(const float4*)(Wg + (size_t)(d0 + u) * 8 + 4);
    p[0] += v[u] * g0.x; p[1] += v[u] * g0.y; p[2] += v[u] * g0.z; p[3] += v[u] * g0.w;
    p[4] += v[u] * g1.x; p[5] += v[u] * g1.y; p[6] += v[u] * g1.z; p[7] += v[u] * g1.w;
  }
  for (int o = 32; o > 0; o >>= 1)
    for (int ee = 0; ee < 8; ++ee) p[ee] += __shfl_xor(p[ee], o);
  if (lane == 0) {
    float mx = -1e30f;
    for (int ee = 0; ee < 8; ++ee) mx = fmaxf(mx, p[ee]);
    for (int ee = 0; ee < 8; ++ee) p[ee] = __expf(p[ee] - mx);
    int i1 = 0; float v1 = p[0];
    for (int ee = 1; ee < 8; ++ee) if (p[ee] > v1) { v1 = p[ee]; i1 = ee; }
    int i2 = -1; float v2 = -1.f;
    for (int ee = 0; ee < 8; ++ee) if (ee != i1 && p[ee] > v2) { v2 = p[ee]; i2 = ee; }
    float ws = v1 + v2;
    tokexp[t * 2] = i1; tokexp[t * 2 + 1] = i2;
    tokgate[t * 2] = v1 / ws; tokgate[t * 2 + 1] = v2 / ws;
  }
}

// ---------------- count: LDS histogram, 8 global atomics per block ----------------
__global__ __launch_bounds__(256) void k_count(const int* __restrict__ tokexp,
                                               int* __restrict__ counts) {
  __shared__ int lc[8];
  if (threadIdx.x < 8) lc[threadIdx.x] = 0;
  __syncthreads();
  int i = blockIdx.x * 256 + threadIdx.x;
  atomicAdd(&lc[tokexp[i]], 1);
  __syncthreads();
  if (threadIdx.x < 8) atomicAdd(&counts[threadIdx.x], lc[threadIdx.x]);
}

// ---------------- MoE setup ----------------
__global__ __launch_bounds__(256) void k_moe_setup(const int* __restrict__ counts,
                                                   int* __restrict__ segstart,
                                                   int* __restrict__ tileexp,
                                                   int* __restrict__ rowtok) {
  __shared__ int ss[9], cc[8];
  if (threadIdx.x < 8) cc[threadIdx.x] = counts[threadIdx.x];
  __syncthreads();
  if (threadIdx.x == 0) {
    int off = 0;
    for (int e = 0; e < 8; ++e) { ss[e] = off; off += ((cc[e] + 127) >> 7) << 7; }
    ss[8] = off;
    for (int e = 0; e < 9; ++e) segstart[e] = ss[e];
  }
  __syncthreads();
  for (int tl = threadIdx.x; tl < NTILES; tl += 256) {
    int ex;
    if (tl >= 200) ex = 9;
    else if (tl >= 136) ex = 8;
    else {
      int row = tl * 128; ex = -1;
      for (int i = 0; i < 8; ++i)
        if (row >= ss[i] && row < ss[i + 1]) { ex = i; break; }
    }
    tileexp[tl] = ex;
  }
  for (int e = 0; e < 8; ++e) {
    int cnt = cc[e], cap = ((cnt + 127) >> 7) << 7;
    for (int r = cnt + threadIdx.x; r < cap; r += 256)
      rowtok[ss[e] + r] = -1;
  }
}

// ---------------- assign rows ----------------
__global__ __launch_bounds__(256) void k_assign(const int* __restrict__ tokexp,
                                                int* __restrict__ fill,
                                                const int* __restrict__ segstart,
                                                int* __restrict__ rowtok,
                                                int* __restrict__ tokslot) {
  __shared__ int lcnt[8], lbase[8];
  if (threadIdx.x < 8) lcnt[threadIdx.x] = 0;
  __syncthreads();
  int t = blockIdx.x * 256 + threadIdx.x;
  int e0 = tokexp[t * 2], e1 = tokexp[t * 2 + 1];
  int r0 = atomicAdd(&lcnt[e0], 1);
  int r1 = atomicAdd(&lcnt[e1], 1);
  __syncthreads();
  if (threadIdx.x < 8) lbase[threadIdx.x] = atomicAdd(&fill[threadIdx.x], lcnt[threadIdx.x]);
  __syncthreads();
  int p0 = segstart[e0] + lbase[e0] + r0;
  int p1 = segstart[e1] + lbase[e1] + r1;
  rowtok[p0] = t; rowtok[p1] = t;
  tokslot[t * 2] = p0; tokslot[t * 2 + 1] = p1;
  rowtok[SH0_ROW + t] = t;
  rowtok[SH1_ROW + t] = t;
}

// ---------------- combine ----------------
__global__ __launch_bounds__(256) void k_combine(const float* __restrict__ x2f,
                                                 const bf16* __restrict__ Yg,
                                                 const int* __restrict__ tokslot,
                                                 const float* __restrict__ tokgate,
                                                 float* __restrict__ out_x) {
  int t = blockIdx.x * 4 + (threadIdx.x >> 6);
  int lane = threadIdx.x & 63;
  int s1 = tokslot[t * 2], s2 = tokslot[t * 2 + 1];
  float g1 = tokgate[t * 2], g2 = tokgate[t * 2 + 1];
  int d0 = lane * 8;
  short8 a = *(const short8*)(Yg + (size_t)s1 * 512 + d0);
  short8 b = *(const short8*)(Yg + (size_t)s2 * 512 + d0);
  short8 c = *(const short8*)(Yg + (size_t)(SH0_ROW + t) * 512 + d0);
  short8 d = *(const short8*)(Yg + (size_t)(SH1_ROW + t) * 512 + d0);
  const float* xr = x2f + (size_t)t * 512 + d0;
  float* outr = out_x + (size_t)t * 512 + d0;
  for (int u = 0; u < 8; ++u)
    outr[u] = xr[u] + g1 * b2f(a[u]) + g2 * b2f(b[u]) + b2f(c[u]) + b2f(d[u]);
}

// ---------------- host ----------------
extern "C" void kernel_launch(void* const* d_in, const int* in_sizes, int n_in,
                              void* d_out, int out_size, void* d_ws, size_t ws_size,
                              hipStream_t stream) {
  const float* x    = (const float*)d_in[0];
  const float* n2w  = (const float*)d_in[1];
  const float* Wdq  = (const float*)d_in[2];
  const float* qnw  = (const float*)d_in[3];
  const float* Wuq  = (const float*)d_in[4];
  const float* Wdkv = (const float*)d_in[5];
  const float* kvnw = (const float*)d_in[6];
  const float* Wukv = (const float*)d_in[7];
  const float* Wo   = (const float*)d_in[8];
  const float* Wg   = (const float*)d_in[9];
  const float* We1  = (const float*)d_in[10];
  const float* We2  = (const float*)d_in[11];
  const float* Ws1  = (const float*)d_in[12];
  const float* Ws2  = (const float*)d_in[13];

  float* out_x  = (float*)d_out;
  float* out_kv = out_x + (size_t)4 * 2048 * 512;

  char* base = (char*)d_ws;
  size_t off = 0;
  auto alloc = [&](size_t bytes) -> void* {
    void* p = base + off;
    off += (bytes + 255) & ~(size_t)255;
    return p;
  };
  const size_t T = 8192;
  // ---- persistent region ----
  bf16*  WcatT = (bf16*)alloc(352 * 512 * 2);
  bf16*  WuqT  = (bf16*)alloc(384 * 192 * 2);
  bf16*  WukvT = (bf16*)alloc(768 * 128 * 2);
  bf16*  WoT   = (bf16*)alloc(512 * 512 * 2);
  bf16*  W1T   = (bf16*)alloc((size_t)10 * 1024 * 512 * 2);
  bf16*  W2T   = (bf16*)alloc((size_t)10 * 512 * 1024 * 2);
  float* x2f   = (float*)alloc(T * 512 * 4);
  bf16*  x2b   = (bf16*)alloc(T * 512 * 2);
  int*   tokexp  = (int*)alloc(T * 2 * 4);
  float* tokgate = (float*)alloc(T * 2 * 4);
  int*   tokslot = (int*)alloc(T * 2 * 4);
  int*   rowtok  = (int*)alloc(ROWCAP * 4);
  int*   segstart= (int*)alloc(16 * 4);
  int*   tileexp = (int*)alloc(NTILES * 4);
  int*   cnts    = (int*)alloc(16 * 4);
  float* ropet   = (float*)alloc(2048 * 32 * 4);

  // ---- scratch region (NO aliasing; MoE phase reuses S from the top) ----
  char* S = base + off;
  size_t soff = 0;
  auto salloc = [&](size_t bytes) -> void* {
    void* p = S + soff;
    soff += (bytes + 255) & ~(size_t)255;
    return p;
  };
  bf16*  xb    = (bf16*)salloc(T * 512 * 2);
  float* tmp0  = (float*)salloc(T * 352 * 4);
  bf16*  cq    = (bf16*)salloc(T * 192 * 2);
  bf16*  kvn   = (bf16*)salloc(T * 128 * 2);
  float* krope = (float*)salloc(T * 32 * 4);
  bf16*  kvbig = (bf16*)salloc(T * 768 * 2);
  bf16*  qf    = (bf16*)salloc(T * 384 * 2);
  bf16*  kf    = (bf16*)salloc(T * 384 * 2);
  bf16*  vT    = (bf16*)salloc(T * 512 * 2);
  bf16*  attnb = (bf16*)salloc(T * 512 * 2);
  bf16*  woout = (bf16*)salloc(T * 512 * 2);
  bf16*  pO    = (bf16*)salloc((size_t)16 * NPART * 4096 * 2);  // 36.7 MB
  float* pML   = (float*)salloc((size_t)16 * NPART * 64 * 4);
  size_t attn_ws = soff;
  bf16* Hg = (bf16*)S;
  bf16* Yg = (bf16*)(S + (size_t)ROWCAP * 1024 * 2 + 256);
  size_t moe_ws = (size_t)ROWCAP * 1024 * 2 + 256 + (size_t)ROWCAP * 512 * 2;
  size_t need = off + (attn_ws > moe_ws ? attn_ws : moe_ws);
  if (need > ws_size) return;

  hipMemsetAsync(cnts, 0, 64, stream);

  // x -> bf16 ; rope table
  k_f32_to_bf16<<<(int)((T * 512 + 255) / 256), 256, 0, stream>>>(x, xb, (int)(T * 512));
  k_rope_table<<<128, 256, 0, stream>>>(ropet);

  // all weight transposes in ONE kernel
  {
    Tall TT;
    auto mk = [](const float* s, bf16* d, int K, int N, int ldo, int nz,
                 long inZ, long outZ, int start) -> TD {
      TD t; t.src = s; t.dst = d; t.K = K; t.N = N; t.ldo = ldo;
      t.bx = (K + 63) / 64; t.bxy = t.bx * ((N + 63) / 64);
      t.start = start; t.inZ = inZ; t.outZ = outZ; (void)nz; return t;
    };
    int st = 0;
    TT.d[0] = mk(Wdq,  WcatT,             512, 192, 512, 1, 0, 0, st); st += 24;
    TT.d[1] = mk(Wdkv, WcatT + 192 * 512, 512, 160, 512, 1, 0, 0, st); st += 24;
    TT.d[2] = mk(Wuq,  WuqT,  192, 384, 192, 1, 0, 0, st); st += 18;
    TT.d[3] = mk(Wukv, WukvT, 128, 768, 128, 1, 0, 0, st); st += 24;
    TT.d[4] = mk(Wo,   WoT,   512, 512, 512, 1, 0, 0, st); st += 64;
    TT.d[5] = mk(We1, W1T, 512, 1024, 512, 8, (long)512 * 1024, (long)1024 * 512, st); st += 1024;
    TT.d[6] = mk(Ws1, W1T + (size_t)8 * 1024 * 512, 512, 1024, 512, 2,
                 (long)512 * 1024, (long)1024 * 512, st); st += 256;
    TT.d[7] = mk(We2, W2T, 1024, 512, 1024, 8, (long)1024 * 512, (long)512 * 1024, st); st += 1024;
    TT.d[8] = mk(Ws2, W2T + (size_t)8 * 512 * 1024, 1024, 512, 1024, 2,
                 (long)1024 * 512, (long)512 * 1024, st); st += 256;
    k_transpose_all<<<st, 256, 0, stream>>>(TT);
  }

  // x @ [W_dq | W_dkv] -> tmp0 (f32), then norms/splits (+ f32 kv output)
  k_gemm_dq<<<dim3(64, 3), 256, 0, stream>>>(xb, WcatT, 352, 512, 512, 512, 352, tmp0);
  k_postproj1<<<2048, 256, 0, stream>>>(tmp0, qnw, kvnw, cq, kvn, krope, out_kv);

  // q path: GEMM with fused rope -> qf directly
  k_gemm_q<<<dim3(64, 3), 256, 0, stream>>>(cq, WuqT, ropet, qf);

  // kv path
  k_gemm_kv<<<dim3(64, 6), 256, 0, stream>>>(kvn, WukvT, 768, 128, 128, 128, 768, kvbig);
  k_make_kf<<<12288, 256, 0, stream>>>(kvbig, krope, ropet, kf);
  k_make_vT<<<dim3(32, 16), 256, 0, stream>>>(kvbig, vT);

  // attention: 1D grid with bh-per-XCD locality + merge (bands 1-7)
  k_flash<<<NCHUNK * 16, 64, 0, stream>>>(qf, kf, vT, attnb, pO, pML);
  k_merge<<<dim3(56, 16), 512, 0, stream>>>(pO, pML, attnb);

  // W_o (bf16 out), fused residual+norm2+gating
  k_gemm_wo<<<dim3(64, 4), 256, 0, stream>>>(attnb, WoT, 512, 512, 512, 512, 512, woout);
  k_norm2g<<<2048, 256, 0, stream>>>(x, woout, n2w, Wg, x2f, x2b, tokexp, tokgate);
  k_count<<<64, 256, 0, stream>>>(tokexp, cnts);
  k_moe_setup<<<1, 256, 0, stream>>>(cnts, segstart, tileexp, rowtok);
  k_assign<<<32, 256, 0, stream>>>(tokexp, cnts + 8, segstart, rowtok, tokslot);

  // sparse MoE: grouped up (silu) -> grouped down -> combine (XCD tile slices)
  k_gemm_grouped<1><<<dim3(NTILES, 8), 256, 0, stream>>>(
      x2b, rowtok, tileexp, W1T, (size_t)1024 * 512, 1024, 512, 512, Hg, 1024);
  k_gemm_grouped<0><<<dim3(NTILES, 4), 256, 0, stream>>>(
      Hg, nullptr, tileexp, W2T, (size_t)512 * 1024, 512, 1024, 1024, Yg, 512);
  k_combine<<<2048, 256, 0, stream>>>(x2f, Yg, tokslot, tokgate, out_x);
}